// Round 2
// baseline (1695.957 us; speedup 1.0000x reference)
//
#include <hip/hip_runtime.h>
#include <math.h>

// Problem constants (fixed by the reference)
#define BB   2
#define SS   2304
#define DINC 1024
#define DIMC 1024
#define HH   16
#define HD   64

// ---------------------------------------------------------------------------
// GEMM (NT): C[m][n] = sum_k A[m][k] * Bw[n][k] + bias[n]
// Both A and Bw are row-major with K contiguous -> row-row dot products.
// BM x BN block tile, BK k-tile, TM x TN per-thread micro-tile, 256 threads.
// TN is split into TN/4 float4 column-chunks spaced BN/(TN/4) apart so that
// B-fragment LDS reads span 256 contiguous bytes across the 16 tc lanes
// (2-way bank aliasing = free; the naive tc*TN layout was a 4-way conflict).
// All problem dims divide the tiles evenly; no bounds checks needed.
// ---------------------------------------------------------------------------
template<int BM, int BN, int BK, int TM, int TN>
__global__ __launch_bounds__(256)
void gemm_nt_bias(const float* __restrict__ A, const float* __restrict__ Bw,
                  const float* __restrict__ bias, float* __restrict__ C,
                  int M, int N, int K)
{
    __shared__ float As[BK][BM];   // [k][m] (transposed on store)
    __shared__ float Bs[BK][BN];   // [k][n]

    constexpr int NC = TN / 4;         // column chunks per thread
    constexpr int CS = BN / NC;        // chunk stride in columns

    const int t  = threadIdx.x;
    const int bm = blockIdx.y * BM;
    const int bn = blockIdx.x * BN;
    const int tr = t / 16;             // 0..15, rows tr*TM..
    const int tc = t % 16;             // 0..15, col base tc*4 within each chunk

    float acc[TM][TN];
    #pragma unroll
    for (int i = 0; i < TM; ++i)
        #pragma unroll
        for (int j = 0; j < TN; ++j) acc[i][j] = 0.f;

    for (int k0 = 0; k0 < K; k0 += BK) {
        // ---- stage A tile (BM x BK) ----
        #pragma unroll
        for (int u = 0; u < (BM * BK) / 1024; ++u) {
            int e   = (t + u * 256) * 4;
            int row = e / BK;
            int kk  = e % BK;
            float4 v4 = *(const float4*)(A + (size_t)(bm + row) * K + k0 + kk);
            As[kk + 0][row] = v4.x; As[kk + 1][row] = v4.y;
            As[kk + 2][row] = v4.z; As[kk + 3][row] = v4.w;
        }
        // ---- stage B tile (BN x BK) ----
        #pragma unroll
        for (int u = 0; u < (BN * BK) / 1024; ++u) {
            int e   = (t + u * 256) * 4;
            int row = e / BK;
            int kk  = e % BK;
            float4 v4 = *(const float4*)(Bw + (size_t)(bn + row) * K + k0 + kk);
            Bs[kk + 0][row] = v4.x; Bs[kk + 1][row] = v4.y;
            Bs[kk + 2][row] = v4.z; Bs[kk + 3][row] = v4.w;
        }
        __syncthreads();

        #pragma unroll
        for (int kk = 0; kk < BK; ++kk) {
            float ar[TM], br[TN];
            #pragma unroll
            for (int i = 0; i < TM; i += 4)
                *(float4*)&ar[i] = *(const float4*)&As[kk][tr * TM + i];
            #pragma unroll
            for (int q = 0; q < NC; ++q)
                *(float4*)&br[4 * q] = *(const float4*)&Bs[kk][q * CS + tc * 4];
            #pragma unroll
            for (int i = 0; i < TM; ++i)
                #pragma unroll
                for (int j = 0; j < TN; ++j)
                    acc[i][j] = fmaf(ar[i], br[j], acc[i][j]);
        }
        __syncthreads();
    }

    // epilogue: +bias, coalesced float4 stores (one per column chunk)
    #pragma unroll
    for (int i = 0; i < TM; ++i) {
        #pragma unroll
        for (int q = 0; q < NC; ++q) {
            int col = bn + q * CS + tc * 4;
            float4 bi = *(const float4*)(bias + col);
            float4 o;
            o.x = acc[i][4 * q + 0] + bi.x;
            o.y = acc[i][4 * q + 1] + bi.y;
            o.z = acc[i][4 * q + 2] + bi.z;
            o.w = acc[i][4 * q + 3] + bi.w;
            *(float4*)(C + (size_t)(bm + tr * TM + i) * N + col) = o;
        }
    }
}

// ---------------------------------------------------------------------------
// Fused RMSNorm (over full DIM=1024) + axial 2D RoPE, in-place on q and k
// rows of the qkv buffer. One block (256 threads) per token.
// RoPE: head dim 64; dims [0,32) keyed by row position, [32,64) by col.
// Within each 32-dim half: pair (j, j+16), freq = 10000^(-j/16).
// ---------------------------------------------------------------------------
__global__ __launch_bounds__(256)
void normrope_kernel(float* __restrict__ qkv, const float* __restrict__ q_scale,
                     const float* __restrict__ k_scale, const int* __restrict__ wptr)
{
    const int token = blockIdx.x;        // 0 .. B*S-1
    const int s     = token % SS;
    const int w     = *wptr;
    const int t     = threadIdx.x;
    const float rowp = (float)(s / w);
    const float colp = (float)(s % w);

    float* base = qkv + (size_t)token * (3 * DIMC);

    __shared__ float buf[DIMC];
    __shared__ float red[4];

    #pragma unroll
    for (int sel = 0; sel < 2; ++sel) {
        float*       row = base + sel * DIMC;
        const float* scp = sel ? k_scale : q_scale;

        float4 x = *(const float4*)(row + 4 * t);
        float ss = x.x * x.x + x.y * x.y + x.z * x.z + x.w * x.w;
        #pragma unroll
        for (int o = 32; o >= 1; o >>= 1) ss += __shfl_xor(ss, o);
        if ((t & 63) == 0) red[t >> 6] = ss;
        __syncthreads();

        float rinv = rsqrtf((red[0] + red[1] + red[2] + red[3]) * (1.0f / DIMC) + 1e-6f);
        float4 g = *(const float4*)(scp + 4 * t);
        buf[4 * t + 0] = x.x * rinv * g.x;
        buf[4 * t + 1] = x.y * rinv * g.y;
        buf[4 * t + 2] = x.z * rinv * g.z;
        buf[4 * t + 3] = x.w * rinv * g.w;
        __syncthreads();

        // 512 rotation pairs, 2 per thread
        #pragma unroll
        for (int pp = 0; pp < 2; ++pp) {
            int p = t + pp * 256;
            int h = p >> 5;                 // head
            int r = p & 31;                 // pair index within head
            int j = r & 15;                 // frequency index
            float pos = (r < 16) ? rowp : colp;
            int d1 = h * HD + ((r < 16) ? j : (32 + j));
            int d2 = d1 + 16;
            float freq = powf(10000.0f, -(float)j * (1.0f / 16.0f));
            float ang  = pos * freq;
            float cs = cosf(ang), sn = sinf(ang);
            float x1 = buf[d1], x2 = buf[d2];
            row[d1] = x1 * cs - x2 * sn;
            row[d2] = x2 * cs + x1 * sn;
        }
        __syncthreads();   // buf/red reused by next sel
    }
}

// ---------------------------------------------------------------------------
// Flash attention, fp32, one block per (q-tile of 64 rows, b*h).
// Q/K stored transposed in LDS ([d][i]) so score fragments are float4 reads;
// P round-trips through LDS ([j][i]) for the PV product. Online softmax.
// 256 threads: thread t -> row group r=t/16 (rows 4r..4r+3),
//                          col group c=t%16 (cols/dims 4c..4c+3).
// Row statistics reduce over the 16 contiguous lanes sharing r (in-wave).
// ---------------------------------------------------------------------------
__global__ __launch_bounds__(256)
void flash_attn(const float* __restrict__ qkv, float* __restrict__ outp)
{
    const int qt = blockIdx.x;           // 0..S/64-1
    const int bh = blockIdx.y;           // 0..B*H-1
    const int b  = bh / HH, h = bh % HH;
    const int t  = threadIdx.x;
    const int r  = t >> 4;               // 0..15
    const int c  = t & 15;               // 0..15

    __shared__ float Qs[HD][64];         // [d][i]
    __shared__ float Ks[HD][64];         // [d][j]
    __shared__ float Vs[64][HD];         // [j][d]
    __shared__ float Ps[64][64];         // [j][i]

    const size_t rstride = 3 * DIMC;
    const float* qb = qkv + (size_t)b * SS * rstride + h * HD;
    const float* kb = qb + DIMC;
    const float* vb = qb + 2 * DIMC;
    const int q0 = qt * 64;

    // load Q tile (scale 1/sqrt(64) folded in), transposed
    {
        const int i  = t >> 2;
        const int d0 = (t & 3) * 16;
        const float* p = qb + (size_t)(q0 + i) * rstride + d0;
        #pragma unroll
        for (int u = 0; u < 4; ++u) {
            float4 v4 = *(const float4*)(p + 4 * u);
            Qs[d0 + 4 * u + 0][i] = v4.x * 0.125f;
            Qs[d0 + 4 * u + 1][i] = v4.y * 0.125f;
            Qs[d0 + 4 * u + 2][i] = v4.z * 0.125f;
            Qs[d0 + 4 * u + 3][i] = v4.w * 0.125f;
        }
    }

    float m_i[4], l_i[4], O[4][4];
    #pragma unroll
    for (int i = 0; i < 4; ++i) {
        m_i[i] = -INFINITY;
        l_i[i] = 0.f;
        #pragma unroll
        for (int j = 0; j < 4; ++j) O[i][j] = 0.f;
    }

    for (int k0 = 0; k0 < SS; k0 += 64) {
        __syncthreads();   // prior tile fully consumed (also covers Q store, iter 0)
        // stage K (transposed) and V tiles
        {
            const int j  = t >> 2;
            const int d0 = (t & 3) * 16;
            const float* kp = kb + (size_t)(k0 + j) * rstride + d0;
            #pragma unroll
            for (int u = 0; u < 4; ++u) {
                float4 v4 = *(const float4*)(kp + 4 * u);
                Ks[d0 + 4 * u + 0][j] = v4.x;
                Ks[d0 + 4 * u + 1][j] = v4.y;
                Ks[d0 + 4 * u + 2][j] = v4.z;
                Ks[d0 + 4 * u + 3][j] = v4.w;
            }
            const float* vp = vb + (size_t)(k0 + j) * rstride + d0;
            #pragma unroll
            for (int u = 0; u < 4; ++u)
                *(float4*)&Vs[j][d0 + 4 * u] = *(const float4*)(vp + 4 * u);
        }
        __syncthreads();

        // ---- scores: 4x4 micro-tile per thread ----
        float sc[4][4];
        #pragma unroll
        for (int i = 0; i < 4; ++i)
            #pragma unroll
            for (int j = 0; j < 4; ++j) sc[i][j] = 0.f;

        #pragma unroll
        for (int d = 0; d < HD; ++d) {
            float4 q4 = *(const float4*)&Qs[d][4 * r];
            float4 k4 = *(const float4*)&Ks[d][4 * c];
            float qa[4] = {q4.x, q4.y, q4.z, q4.w};
            float ka[4] = {k4.x, k4.y, k4.z, k4.w};
            #pragma unroll
            for (int i = 0; i < 4; ++i)
                #pragma unroll
                for (int j = 0; j < 4; ++j)
                    sc[i][j] = fmaf(qa[i], ka[j], sc[i][j]);
        }

        // ---- online softmax update (per owned row) ----
        #pragma unroll
        for (int i = 0; i < 4; ++i) {
            float mx = fmaxf(fmaxf(sc[i][0], sc[i][1]), fmaxf(sc[i][2], sc[i][3]));
            #pragma unroll
            for (int o = 1; o < 16; o <<= 1) mx = fmaxf(mx, __shfl_xor(mx, o));
            float mn    = fmaxf(m_i[i], mx);
            float alpha = __expf(m_i[i] - mn);
            m_i[i] = mn;
            float sum = 0.f;
            #pragma unroll
            for (int j = 0; j < 4; ++j) {
                sc[i][j] = __expf(sc[i][j] - mn);
                sum += sc[i][j];
            }
            #pragma unroll
            for (int o = 1; o < 16; o <<= 1) sum += __shfl_xor(sum, o);
            l_i[i] = l_i[i] * alpha + sum;
            #pragma unroll
            for (int j = 0; j < 4; ++j) O[i][j] *= alpha;
        }

        // ---- write P to LDS ([j][i], i contiguous for float4) ----
        #pragma unroll
        for (int j = 0; j < 4; ++j) {
            float4 pv = make_float4(sc[0][j], sc[1][j], sc[2][j], sc[3][j]);
            *(float4*)&Ps[4 * c + j][4 * r] = pv;
        }
        __syncthreads();

        // ---- O += P @ V : rows 4r.., dims 4c.. ----
        #pragma unroll
        for (int j = 0; j < 64; ++j) {
            float4 p4 = *(const float4*)&Ps[j][4 * r];
            float4 v4 = *(const float4*)&Vs[j][4 * c];
            float pa[4] = {p4.x, p4.y, p4.z, p4.w};
            float va[4] = {v4.x, v4.y, v4.z, v4.w};
            #pragma unroll
            for (int i = 0; i < 4; ++i)
                #pragma unroll
                for (int d = 0; d < 4; ++d)
                    O[i][d] = fmaf(pa[i], va[d], O[i][d]);
        }
    }

    // epilogue: normalize, store to (B,S,DIM) with dim = h*64 + 4c + d
    #pragma unroll
    for (int i = 0; i < 4; ++i) {
        float inv = 1.0f / l_i[i];
        float4 o4 = make_float4(O[i][0] * inv, O[i][1] * inv, O[i][2] * inv, O[i][3] * inv);
        int row = q0 + 4 * r + i;
        *(float4*)(outp + ((size_t)b * SS + row) * DIMC + h * HD + 4 * c) = o4;
    }
}

// ---------------------------------------------------------------------------
// Launch
// ---------------------------------------------------------------------------
extern "C" void kernel_launch(void* const* d_in, const int* in_sizes, int n_in,
                              void* d_out, int out_size, void* d_ws, size_t ws_size,
                              hipStream_t stream)
{
    const float* input   = (const float*)d_in[0];
    const float* qkv_w   = (const float*)d_in[1];
    const float* qkv_b   = (const float*)d_in[2];
    const float* q_scale = (const float*)d_in[3];
    const float* k_scale = (const float*)d_in[4];
    const float* proj_w  = (const float*)d_in[5];
    const float* proj_b  = (const float*)d_in[6];
    const int*   width   = (const int*)d_in[8];
    float* out = (float*)d_out;

    // workspace layout: qkv (B*S*3*DIM f32) | attn_out (B*S*DIM f32) = 75.5 MB
    float* qkv  = (float*)d_ws;
    float* attn = qkv + (size_t)BB * SS * 3 * DIMC;

    const int M = BB * SS;   // 4608

    // 1) QKV = input @ qkv_w^T + qkv_b   (4608 x 3072 x 1024)
    {
        dim3 grid(3 * DIMC / 128, M / 128);
        gemm_nt_bias<128, 128, 16, 8, 8><<<grid, 256, 0, stream>>>(
            input, qkv_w, qkv_b, qkv, M, 3 * DIMC, DINC);
    }

    // 2) RMSNorm + 2D RoPE on q,k (in place)
    normrope_kernel<<<BB * SS, 256, 0, stream>>>(qkv, q_scale, k_scale, width);

    // 3) flash attention -> attn (B,S,DIM)
    {
        dim3 grid(SS / 64, BB * HH);
        flash_attn<<<grid, 256, 0, stream>>>(qkv, attn);
    }

    // 4) out = attn @ proj_w^T + proj_b   (4608 x 1024 x 1024)
    {
        dim3 grid(DINC / 64, M / 128);
        gemm_nt_bias<128, 64, 16, 8, 4><<<grid, 256, 0, stream>>>(
            attn, proj_w, proj_b, out, M, DINC, DIMC);
    }
}

// Round 3
// 809.855 us; speedup vs baseline: 2.0941x; 2.0941x over previous
//
#include <hip/hip_runtime.h>
#include <math.h>

// Problem constants (fixed by the reference)
#define BB   2
#define SS   2304
#define DINC 1024
#define DIMC 1024
#define HH   16
#define HD   64

typedef _Float16 half_t;
typedef __attribute__((ext_vector_type(4))) _Float16 half4;   // 2 VGPRs
typedef __attribute__((ext_vector_type(4))) float    f32x4;   // 4 VGPRs

// ---------------------------------------------------------------------------
// GEMM (NT): C[m][n] = sum_k A[m][k] * Bw[n][k] + bias[n]   (fp32, unchanged)
// ---------------------------------------------------------------------------
template<int BM, int BN, int BK, int TM, int TN>
__global__ __launch_bounds__(256)
void gemm_nt_bias(const float* __restrict__ A, const float* __restrict__ Bw,
                  const float* __restrict__ bias, float* __restrict__ C,
                  int M, int N, int K)
{
    __shared__ float As[BK][BM];   // [k][m]
    __shared__ float Bs[BK][BN];   // [k][n]

    constexpr int NC = TN / 4;     // column chunks per thread
    constexpr int CS = BN / NC;    // chunk stride

    const int t  = threadIdx.x;
    const int bm = blockIdx.y * BM;
    const int bn = blockIdx.x * BN;
    const int tr = t / 16;
    const int tc = t % 16;

    float acc[TM][TN];
    #pragma unroll
    for (int i = 0; i < TM; ++i)
        #pragma unroll
        for (int j = 0; j < TN; ++j) acc[i][j] = 0.f;

    for (int k0 = 0; k0 < K; k0 += BK) {
        #pragma unroll
        for (int u = 0; u < (BM * BK) / 1024; ++u) {
            int e   = (t + u * 256) * 4;
            int row = e / BK;
            int kk  = e % BK;
            float4 v4 = *(const float4*)(A + (size_t)(bm + row) * K + k0 + kk);
            As[kk + 0][row] = v4.x; As[kk + 1][row] = v4.y;
            As[kk + 2][row] = v4.z; As[kk + 3][row] = v4.w;
        }
        #pragma unroll
        for (int u = 0; u < (BN * BK) / 1024; ++u) {
            int e   = (t + u * 256) * 4;
            int row = e / BK;
            int kk  = e % BK;
            float4 v4 = *(const float4*)(Bw + (size_t)(bn + row) * K + k0 + kk);
            Bs[kk + 0][row] = v4.x; Bs[kk + 1][row] = v4.y;
            Bs[kk + 2][row] = v4.z; Bs[kk + 3][row] = v4.w;
        }
        __syncthreads();

        #pragma unroll
        for (int kk = 0; kk < BK; ++kk) {
            float ar[TM], br[TN];
            #pragma unroll
            for (int i = 0; i < TM; i += 4)
                *(float4*)&ar[i] = *(const float4*)&As[kk][tr * TM + i];
            #pragma unroll
            for (int q = 0; q < NC; ++q)
                *(float4*)&br[4 * q] = *(const float4*)&Bs[kk][q * CS + tc * 4];
            #pragma unroll
            for (int i = 0; i < TM; ++i)
                #pragma unroll
                for (int j = 0; j < TN; ++j)
                    acc[i][j] = fmaf(ar[i], br[j], acc[i][j]);
        }
        __syncthreads();
    }

    #pragma unroll
    for (int i = 0; i < TM; ++i) {
        #pragma unroll
        for (int q = 0; q < NC; ++q) {
            int col = bn + q * CS + tc * 4;
            float4 bi = *(const float4*)(bias + col);
            float4 o;
            o.x = acc[i][4 * q + 0] + bi.x;
            o.y = acc[i][4 * q + 1] + bi.y;
            o.z = acc[i][4 * q + 2] + bi.z;
            o.w = acc[i][4 * q + 3] + bi.w;
            *(float4*)(C + (size_t)(bm + tr * TM + i) * N + col) = o;
        }
    }
}

// ---------------------------------------------------------------------------
// RMSNorm + axial 2D RoPE, producing f16 operands for the MFMA attention.
//  - Qh (q*0.125, rotated) -> halfs [0,1024)   of the token's qkv slot (overlay)
//  - Kh (rotated)          -> halfs [1024,2048) of the token's qkv slot (overlay)
//  - Vf: V cast to f16 in MFMA A-fragment-stream layout, separate buffer:
//    Vf[(bh*144 + (s>>4))*1024 + (((s&15)>>2)*16 + (d&15))*16 + (d>>4)*4 + (s&3)]
// Overlay safety: Qh/Kh occupy the q fp32 region (floats [0,1024)); all global
// reads of q happen before the first __syncthreads, writes after it.
// ---------------------------------------------------------------------------
__global__ __launch_bounds__(256)
void normrope_v2(float* __restrict__ qkv, const float* __restrict__ q_scale,
                 const float* __restrict__ k_scale, const int* __restrict__ wptr,
                 half_t* __restrict__ Vf)
{
    const int token = blockIdx.x;        // b*SS + s
    const int s     = token % SS;
    const int b     = token / SS;
    const int w     = *wptr;
    const int t     = threadIdx.x;
    const float rowp = (float)(s / w);
    const float colp = (float)(s % w);

    float* base = qkv + (size_t)token * (3 * DIMC);

    // ---- V -> Vf fragment stream (reads floats [2048,3072), untouched below) ----
    {
        float4 v4 = *(const float4*)(base + 2 * DIMC + 4 * t);
        float vv[4] = {v4.x, v4.y, v4.z, v4.w};
        const int dabs0 = 4 * t;
        const int h  = dabs0 >> 6;
        const int dt = (dabs0 & 63) >> 4;
        const int jq = (s & 15) >> 2;
        const size_t blk = ((size_t)(b * HH + h) * 144 + (s >> 4)) * 1024;
        #pragma unroll
        for (int ii = 0; ii < 4; ++ii) {
            int dl = (dabs0 + ii) & 15;
            Vf[blk + (size_t)(jq * 16 + dl) * 16 + dt * 4 + (s & 3)] = (half_t)vv[ii];
        }
    }

    __shared__ float buf[DIMC];
    __shared__ float red[4];

    #pragma unroll
    for (int sel = 0; sel < 2; ++sel) {
        const float* row = base + sel * DIMC;
        const float* scp = sel ? k_scale : q_scale;

        float4 x = *(const float4*)(row + 4 * t);
        float ss = x.x * x.x + x.y * x.y + x.z * x.z + x.w * x.w;
        #pragma unroll
        for (int o = 32; o >= 1; o >>= 1) ss += __shfl_xor(ss, o);
        if ((t & 63) == 0) red[t >> 6] = ss;
        __syncthreads();

        float rinv = rsqrtf((red[0] + red[1] + red[2] + red[3]) * (1.0f / DIMC) + 1e-6f);
        float4 g = *(const float4*)(scp + 4 * t);
        buf[4 * t + 0] = x.x * rinv * g.x;
        buf[4 * t + 1] = x.y * rinv * g.y;
        buf[4 * t + 2] = x.z * rinv * g.z;
        buf[4 * t + 3] = x.w * rinv * g.w;
        __syncthreads();

        half_t* outh = (half_t*)base + sel * DIMC;   // Qh at halfs [0,1024), Kh at [1024,2048)
        const float qsc = sel ? 1.0f : 0.125f;       // fold 1/sqrt(64) into Q

        #pragma unroll
        for (int pp = 0; pp < 2; ++pp) {
            int p = t + pp * 256;
            int h = p >> 5;
            int r = p & 31;
            int j = r & 15;
            float pos = (r < 16) ? rowp : colp;
            int d1 = h * HD + ((r < 16) ? j : (32 + j));
            int d2 = d1 + 16;
            float freq = powf(10000.0f, -(float)j * (1.0f / 16.0f));
            float ang  = pos * freq;
            float cs = cosf(ang), sn = sinf(ang);
            float x1 = buf[d1], x2 = buf[d2];
            outh[d1] = (half_t)((x1 * cs - x2 * sn) * qsc);
            outh[d2] = (half_t)((x2 * cs + x1 * sn) * qsc);
        }
        __syncthreads();
    }
}

// ---------------------------------------------------------------------------
// Flash attention on the matrix pipe (f16 MFMA 16x16x16, fp32 softmax).
// Key identity: S^T = K.Q^T has C-layout rows j=quad*4+reg, which IS the
// B-operand layout k=quad*4+i needed for O^T = V^T.P^T -> P stays in regs.
// 4 waves per block; wave w owns j-slice [k0+16w, k0+16w+16) per 64-K-tile,
// keeps private online-softmax state, merges via LDS at the epilogue.
// No LDS in the main loop.
// ---------------------------------------------------------------------------
__global__ __launch_bounds__(256)
void flash_attn_mfma(const float* __restrict__ qkv, const half_t* __restrict__ Vf,
                     float* __restrict__ outp)
{
    const int qtb = blockIdx.x;          // 0..35 (64-row q tile)
    const int bh  = blockIdx.y;          // 0..31
    const int b   = bh >> 4, h = bh & 15;
    const int t   = threadIdx.x;
    const int w   = t >> 6;              // wave 0..3
    const int lane = t & 63;
    const int l15 = lane & 15, quad = lane >> 4;

    const half_t* qkvh = (const half_t*)qkv;
    const size_t tokstr = 6144;          // halfs per token slot
    const size_t tb = (size_t)b * SS;
    const int q0 = qtb * 64;

    // ---- Q B-frags (loop invariant): Q[q=qt*16+l15][d=dt*16+quad*4+i] ----
    half4 qf[4][4];
    #pragma unroll
    for (int qt = 0; qt < 4; ++qt)
        #pragma unroll
        for (int dt = 0; dt < 4; ++dt)
            qf[qt][dt] = *(const half4*)(qkvh + (tb + q0 + qt * 16 + l15) * tokstr
                                         + h * HD + dt * 16 + quad * 4);

    f32x4 acc[4][4];                     // [dt][qt] : O^T[d=dt*16+quad*4+reg][q=qt*16+l15]
    float m_i[4], l_i[4];
    #pragma unroll
    for (int qt = 0; qt < 4; ++qt) {
        m_i[qt] = -INFINITY; l_i[qt] = 0.f;
        #pragma unroll
        for (int dt = 0; dt < 4; ++dt) acc[dt][qt] = (f32x4){0.f, 0.f, 0.f, 0.f};
    }

    for (int k0 = 0; k0 < SS; k0 += 64) {
        const int j0 = k0 + 16 * w;      // this wave's 16-row j-slice

        // K A-frags: K[j=j0+l15][d=dt*16+quad*4+i]
        half4 kf[4];
        #pragma unroll
        for (int dt = 0; dt < 4; ++dt)
            kf[dt] = *(const half4*)(qkvh + (tb + j0 + l15) * tokstr + DIMC
                                     + h * HD + dt * 16 + quad * 4);

        // V^T A-frags from the fragment stream (fully coalesced)
        half4 vf[4];
        const half_t* vp = Vf + ((size_t)bh * 144 + (j0 >> 4)) * 1024 + lane * 16;
        #pragma unroll
        for (int dt = 0; dt < 4; ++dt) vf[dt] = *(const half4*)(vp + dt * 4);

        // ---- S^T = K . Q^T  (rows j, cols q) ----
        f32x4 sc[4];
        #pragma unroll
        for (int qt = 0; qt < 4; ++qt) {
            sc[qt] = (f32x4){0.f, 0.f, 0.f, 0.f};
            #pragma unroll
            for (int dt = 0; dt < 4; ++dt)
                sc[qt] = __builtin_amdgcn_mfma_f32_16x16x16f16(kf[dt], qf[qt][dt], sc[qt], 0, 0, 0);
        }

        // ---- online softmax (per q column; lane's 4 regs are 4 j's) ----
        half4 pf[4];
        #pragma unroll
        for (int qt = 0; qt < 4; ++qt) {
            float mx = fmaxf(fmaxf(sc[qt][0], sc[qt][1]), fmaxf(sc[qt][2], sc[qt][3]));
            mx = fmaxf(mx, __shfl_xor(mx, 16));
            mx = fmaxf(mx, __shfl_xor(mx, 32));
            float mn = fmaxf(m_i[qt], mx);
            float alpha = __expf(m_i[qt] - mn);
            m_i[qt] = mn;
            float p0 = __expf(sc[qt][0] - mn);
            float p1 = __expf(sc[qt][1] - mn);
            float p2 = __expf(sc[qt][2] - mn);
            float p3 = __expf(sc[qt][3] - mn);
            float ps = p0 + p1 + p2 + p3;
            ps += __shfl_xor(ps, 16);
            ps += __shfl_xor(ps, 32);
            l_i[qt] = l_i[qt] * alpha + ps;
            #pragma unroll
            for (int dt = 0; dt < 4; ++dt) acc[dt][qt] *= alpha;
            pf[qt] = (half4){(half_t)p0, (half_t)p1, (half_t)p2, (half_t)p3};
        }

        // ---- O^T += V^T . P^T ----
        #pragma unroll
        for (int dt = 0; dt < 4; ++dt)
            #pragma unroll
            for (int qt = 0; qt < 4; ++qt)
                acc[dt][qt] = __builtin_amdgcn_mfma_f32_16x16x16f16(vf[dt], pf[qt], acc[dt][qt], 0, 0, 0);
    }

    // ---- merge the 4 waves' partial (m, l, O^T) ----
    __shared__ float mlb[4][64][2];
    __shared__ float Obuf[64][66];

    if (quad == 0) {
        #pragma unroll
        for (int qt = 0; qt < 4; ++qt) {
            mlb[w][qt * 16 + l15][0] = m_i[qt];
            mlb[w][qt * 16 + l15][1] = l_i[qt];
        }
    }
    __syncthreads();

    float fac[4];
    #pragma unroll
    for (int qt = 0; qt < 4; ++qt) {
        int q = qt * 16 + l15;
        float M = fmaxf(fmaxf(mlb[0][q][0], mlb[1][q][0]), fmaxf(mlb[2][q][0], mlb[3][q][0]));
        float L = mlb[0][q][1] * __expf(mlb[0][q][0] - M)
                + mlb[1][q][1] * __expf(mlb[1][q][0] - M)
                + mlb[2][q][1] * __expf(mlb[2][q][0] - M)
                + mlb[3][q][1] * __expf(mlb[3][q][0] - M);
        fac[qt] = __expf(m_i[qt] - M) / L;
    }

    #pragma unroll
    for (int ph = 0; ph < 4; ++ph) {
        if (w == ph) {
            #pragma unroll
            for (int dt = 0; dt < 4; ++dt)
                #pragma unroll
                for (int qt = 0; qt < 4; ++qt)
                    #pragma unroll
                    for (int rg = 0; rg < 4; ++rg) {
                        int d = dt * 16 + quad * 4 + rg;
                        int q = qt * 16 + l15;
                        float v = acc[dt][qt][rg] * fac[qt];
                        if (ph == 0) Obuf[d][q] = v; else Obuf[d][q] += v;
                    }
        }
        __syncthreads();
    }

    // ---- store O (transpose back): token row q, dims h*64 + d ----
    {
        const int q  = t >> 2;
        const int ds = (t & 3) * 16;
        float* op = outp + (tb + q0 + q) * (size_t)DIMC + h * HD + ds;
        #pragma unroll
        for (int g = 0; g < 4; ++g) {
            float4 o;
            o.x = Obuf[ds + 4 * g + 0][q];
            o.y = Obuf[ds + 4 * g + 1][q];
            o.z = Obuf[ds + 4 * g + 2][q];
            o.w = Obuf[ds + 4 * g + 3][q];
            *(float4*)(op + 4 * g) = o;
        }
    }
}

// ---------------------------------------------------------------------------
// Launch
// ---------------------------------------------------------------------------
extern "C" void kernel_launch(void* const* d_in, const int* in_sizes, int n_in,
                              void* d_out, int out_size, void* d_ws, size_t ws_size,
                              hipStream_t stream)
{
    const float* input   = (const float*)d_in[0];
    const float* qkv_w   = (const float*)d_in[1];
    const float* qkv_b   = (const float*)d_in[2];
    const float* q_scale = (const float*)d_in[3];
    const float* k_scale = (const float*)d_in[4];
    const float* proj_w  = (const float*)d_in[5];
    const float* proj_b  = (const float*)d_in[6];
    const int*   width   = (const int*)d_in[8];
    float* out = (float*)d_out;

    // ws layout: qkv fp32 (56.6 MB, Qh/Kh overlay inside) | attn fp32 (18.9 MB)
    //          | Vf f16 fragment stream (9.4 MB)  => 84.9 MB total
    float*  qkv  = (float*)d_ws;
    float*  attn = qkv + (size_t)BB * SS * 3 * DIMC;
    half_t* Vf   = (half_t*)(attn + (size_t)BB * SS * DIMC);

    const int M = BB * SS;   // 4608

    // 1) QKV = input @ qkv_w^T + qkv_b
    {
        dim3 grid(3 * DIMC / 128, M / 128);
        gemm_nt_bias<128, 128, 16, 8, 8><<<grid, 256, 0, stream>>>(
            input, qkv_w, qkv_b, qkv, M, 3 * DIMC, DINC);
    }

    // 2) RMSNorm + RoPE -> f16 Qh/Kh overlay + Vf stream
    normrope_v2<<<BB * SS, 256, 0, stream>>>(qkv, q_scale, k_scale, width, Vf);

    // 3) MFMA flash attention -> attn (fp32)
    {
        dim3 grid(SS / 64, BB * HH);
        flash_attn_mfma<<<grid, 256, 0, stream>>>(qkv, Vf, attn);
    }

    // 4) out = attn @ proj_w^T + proj_b
    {
        dim3 grid(DINC / 64, M / 128);
        gemm_nt_bias<128, 64, 16, 8, 4><<<grid, 256, 0, stream>>>(
            attn, proj_w, proj_b, out, M, DINC, DIMC);
    }
}

// Round 4
// 333.329 us; speedup vs baseline: 5.0879x; 2.4296x over previous
//
#include <hip/hip_runtime.h>
#include <math.h>

// Problem constants (fixed by the reference)
#define BB   2
#define SS   2304
#define DINC 1024
#define DIMC 1024
#define HH   16
#define HD   64

typedef _Float16 half_t;
typedef __attribute__((ext_vector_type(4))) _Float16 half4;   // 2 VGPRs
typedef __attribute__((ext_vector_type(8))) _Float16 half8;   // 4 VGPRs
typedef __attribute__((ext_vector_type(4))) float    f32x4;   // 4 VGPRs

// async global->LDS, 16B per lane; LDS dest = wave-uniform base + lane*16
#define GLOAD_LDS16(gp, lp)                                                     \
    __builtin_amdgcn_global_load_lds(                                           \
        (const __attribute__((address_space(1))) void*)(gp),                    \
        (__attribute__((address_space(3))) void*)(lp), 16, 0, 0)

// ---------------------------------------------------------------------------
// Converter: fp32 row-major [R][K] -> f16 tile-blocked [R/128][K/32][128][32].
// Tile-blocking makes each 16-row x 32-k chunk a contiguous 1KB so the GEMM
// can stage it with a single wave-wide global_load_lds dwordx4.
// grid (R/128, K/32), 256 threads, 16 elems/thread.
// ---------------------------------------------------------------------------
__global__ __launch_bounds__(256)
void convert_tile_f16(const float* __restrict__ src, half_t* __restrict__ dst, int K)
{
    const int mb = blockIdx.x;
    const int kb = blockIdx.y;
    const int t  = threadIdx.x;
    const int mm = t >> 1;
    const int kk = (t & 1) * 16;
    const float* sp = src + (size_t)(mb * 128 + mm) * K + kb * 32 + kk;
    half_t*      dp = dst + ((size_t)mb * (K >> 5) + kb) * 4096 + mm * 32 + kk;
    #pragma unroll
    for (int g = 0; g < 4; ++g) {
        float4 v = *(const float4*)(sp + 4 * g);
        dp[4 * g + 0] = (half_t)v.x; dp[4 * g + 1] = (half_t)v.y;
        dp[4 * g + 2] = (half_t)v.z; dp[4 * g + 3] = (half_t)v.w;
    }
}

// ---------------------------------------------------------------------------
// f16 MFMA GEMM (NT): C[m][n] = sum_k A[m][k]*W[n][k] + bias[n], fp32 accum.
// m97 structure: 128x128 block tile, BK=32, 4 waves each computing a 64x64
// wave tile as 4x4 grid of 16x16x32 MFMAs. A/W are tile-blocked f16; staging
// via global_load_lds (4 x 1KB wave-loads per wave per K-step).
// C layout per MFMA (m89-verified): col=lane&15, row=quad*4+reg.
// ---------------------------------------------------------------------------
template<bool OUT_HALF>
__global__ __launch_bounds__(256)
void gemm_mfma(const half_t* __restrict__ Ah, const half_t* __restrict__ Bh,
               const float* __restrict__ bias, void* __restrict__ Cout,
               int M, int N, int K)
{
    const int KB = K >> 5;
    __shared__ half_t As[4096];   // [mm 128][kk 32]
    __shared__ half_t Bs[4096];   // [nn 128][kk 32]

    const int t    = threadIdx.x;
    const int w    = t >> 6;
    const int lane = t & 63;
    const int l15  = lane & 15, quad = lane >> 4;
    const int wr   = w >> 1, wc = w & 1;
    const int mb   = blockIdx.y, nb = blockIdx.x;

    f32x4 acc[4][4];
    #pragma unroll
    for (int mt = 0; mt < 4; ++mt)
        #pragma unroll
        for (int nt = 0; nt < 4; ++nt) acc[mt][nt] = (f32x4){0.f, 0.f, 0.f, 0.f};

    const half_t* atile = Ah + (size_t)mb * KB * 4096;
    const half_t* btile = Bh + (size_t)nb * KB * 4096;

    for (int kb = 0; kb < KB; ++kb) {
        const half_t* at = atile + (size_t)kb * 4096;
        const half_t* bt = btile + (size_t)kb * 4096;
        #pragma unroll
        for (int u = 0; u < 2; ++u) {
            const int ch = w * 2 + u;            // 1KB chunk id (0..7)
            GLOAD_LDS16(at + ch * 512 + lane * 8, As + ch * 512);
            GLOAD_LDS16(bt + ch * 512 + lane * 8, Bs + ch * 512);
        }
        __syncthreads();

        half8 af[4], bf[4];
        #pragma unroll
        for (int mt = 0; mt < 4; ++mt)
            af[mt] = *(const half8*)(As + (wr * 64 + mt * 16 + l15) * 32 + quad * 8);
        #pragma unroll
        for (int nt = 0; nt < 4; ++nt)
            bf[nt] = *(const half8*)(Bs + (wc * 64 + nt * 16 + l15) * 32 + quad * 8);

        #pragma unroll
        for (int mt = 0; mt < 4; ++mt)
            #pragma unroll
            for (int nt = 0; nt < 4; ++nt)
                acc[mt][nt] = __builtin_amdgcn_mfma_f32_16x16x32_f16(
                    af[mt], bf[nt], acc[mt][nt], 0, 0, 0);
        __syncthreads();
    }

    // epilogue: D[m = quad*4+reg][n = l15] per 16x16 tile, + bias
    const int bm = mb * 128, bn = nb * 128;
    #pragma unroll
    for (int nt = 0; nt < 4; ++nt) {
        const int n  = bn + wc * 64 + nt * 16 + l15;
        const float bv = bias[n];
        #pragma unroll
        for (int mt = 0; mt < 4; ++mt) {
            const int m0 = bm + wr * 64 + mt * 16 + quad * 4;
            #pragma unroll
            for (int rg = 0; rg < 4; ++rg) {
                const float v = acc[mt][nt][rg] + bv;
                if (OUT_HALF) ((half_t*)Cout)[(size_t)(m0 + rg) * N + n] = (half_t)v;
                else          ((float*) Cout)[(size_t)(m0 + rg) * N + n] = v;
            }
        }
    }
}

// ---------------------------------------------------------------------------
// RMSNorm (full 1024) + axial 2D RoPE on the f16 qkv buffer (fp32 math).
//  - Q (scaled by 0.125, rotated) -> written back in place (halfs [0,1024))
//  - K (rotated) -> Kf coalesced A-fragment stream for the K=32 QK^T MFMA:
//      Kf[(bh*144+jt)*1024 + dt2*512 + lane*8 + i] = K[jt*16+l15][dt2*32+quad*8+i]
//  - V -> Vf coalesced A-fragment stream for the K=16 PV MFMA:
//      Vf[(bh*144+jt)*1024 + dt*256 + lane*4 + i] = V[jt*16+quad*4+i][dt*16+l15]
// ---------------------------------------------------------------------------
__global__ __launch_bounds__(256)
void normrope_v3(half_t* __restrict__ qkvh, const float* __restrict__ q_scale,
                 const float* __restrict__ k_scale, const int* __restrict__ wptr,
                 half_t* __restrict__ Kf, half_t* __restrict__ Vf)
{
    const int token = blockIdx.x;        // b*SS + s
    const int s     = token % SS;
    const int b     = token / SS;
    const int w     = *wptr;
    const int t     = threadIdx.x;
    const float rowp = (float)(s / w);
    const float colp = (float)(s % w);

    half_t* base = qkvh + (size_t)token * 3072;

    // ---- V -> Vf fragment stream ----
    {
        half4 v4 = *(const half4*)(base + 2048 + 4 * t);
        const int dabs0 = 4 * t;
        const int h  = dabs0 >> 6;
        const size_t blk = ((size_t)(b * HH + h) * 144 + (s >> 4)) * 1024;
        const int qv = (s & 15) >> 2;
        const int iv = s & 3;
        #pragma unroll
        for (int ii = 0; ii < 4; ++ii) {
            const int d  = (dabs0 + ii) & 63;
            Vf[blk + (size_t)(d >> 4) * 256 + ((size_t)qv * 16 + (d & 15)) * 4 + iv]
                = v4[ii];
        }
    }

    __shared__ float buf[DIMC];
    __shared__ float red[4];

    #pragma unroll
    for (int sel = 0; sel < 2; ++sel) {
        half_t* row = base + sel * DIMC;
        const float* scp = sel ? k_scale : q_scale;

        half4 xh = *(const half4*)(row + 4 * t);
        float x0 = (float)xh[0], x1 = (float)xh[1], x2 = (float)xh[2], x3 = (float)xh[3];
        float ss = x0 * x0 + x1 * x1 + x2 * x2 + x3 * x3;
        #pragma unroll
        for (int o = 32; o >= 1; o >>= 1) ss += __shfl_xor(ss, o);
        if ((t & 63) == 0) red[t >> 6] = ss;
        __syncthreads();

        const float rinv = rsqrtf((red[0] + red[1] + red[2] + red[3]) * (1.0f / DIMC) + 1e-6f);
        float4 g = *(const float4*)(scp + 4 * t);
        buf[4 * t + 0] = x0 * rinv * g.x;
        buf[4 * t + 1] = x1 * rinv * g.y;
        buf[4 * t + 2] = x2 * rinv * g.z;
        buf[4 * t + 3] = x3 * rinv * g.w;
        __syncthreads();

        const float qsc = sel ? 1.0f : 0.125f;   // fold 1/sqrt(64) into Q

        #pragma unroll
        for (int pp = 0; pp < 2; ++pp) {
            const int p = t + pp * 256;
            const int h = p >> 5;
            const int r = p & 31;
            const int j = r & 15;
            const float pos = (r < 16) ? rowp : colp;
            const int d1 = (r < 16) ? j : (32 + j);   // within-head dim
            const int d2 = d1 + 16;
            const float freq = powf(10000.0f, -(float)j * (1.0f / 16.0f));
            const float ang  = pos * freq;
            const float cs = cosf(ang), sn = sinf(ang);
            const float a1 = buf[h * HD + d1], a2 = buf[h * HD + d2];
            const float o1 = (a1 * cs - a2 * sn) * qsc;
            const float o2 = (a2 * cs + a1 * sn) * qsc;
            if (sel == 0) {
                row[h * HD + d1] = (half_t)o1;
                row[h * HD + d2] = (half_t)o2;
            } else {
                const size_t kblk = ((size_t)(b * HH + h) * 144 + (s >> 4)) * 1024;
                const int l15k = s & 15;
                Kf[kblk + (size_t)(d1 >> 5) * 512
                        + (((size_t)((d1 & 31) >> 3)) * 16 + l15k) * 8 + (d1 & 7)] = (half_t)o1;
                Kf[kblk + (size_t)(d2 >> 5) * 512
                        + (((size_t)((d2 & 31) >> 3)) * 16 + l15k) * 8 + (d2 & 7)] = (half_t)o2;
            }
        }
        __syncthreads();   // buf/red reused by next sel
    }
}

// ---------------------------------------------------------------------------
// Flash attention on the matrix pipe. S^T = K.Q^T via 16x16x32 f16 MFMA
// (C rows j=quad*4+reg == B-operand layout k=quad*4+i for the K=16 PV MFMA,
// so P feeds O^T = V^T.P^T directly from registers). K/V from coalesced
// fragment streams; 4 waves with private online-softmax state over
// interleaved 16-row j-slices; LDS merge at epilogue. Output written f16
// tile-blocked [mb][kb][128][32] as the proj GEMM's A operand.
// ---------------------------------------------------------------------------
__global__ __launch_bounds__(256)
void flash_attn_mfma2(const half_t* __restrict__ qkvh, const half_t* __restrict__ Kf,
                      const half_t* __restrict__ Vf, half_t* __restrict__ attn_h)
{
    const int qtb = blockIdx.x;          // 0..35
    const int bh  = blockIdx.y;          // 0..31
    const int b   = bh >> 4, h = bh & 15;
    const int t   = threadIdx.x;
    const int w   = t >> 6;
    const int lane = t & 63;
    const int l15 = lane & 15, quad = lane >> 4;

    const size_t tb = (size_t)b * SS;
    const int q0 = qtb * 64;

    // Q B-frags (loop invariant): B[k=quad*8+i][n=l15] = Q[q0+qt*16+l15][dt2*32+quad*8+i]
    half8 qf[4][2];
    #pragma unroll
    for (int qt = 0; qt < 4; ++qt)
        #pragma unroll
        for (int dt2 = 0; dt2 < 2; ++dt2)
            qf[qt][dt2] = *(const half8*)(qkvh + (tb + q0 + qt * 16 + l15) * 3072
                                          + h * HD + dt2 * 32 + quad * 8);

    f32x4 acc[4][4];                     // [dt][qt] : O^T[dt*16+quad*4+reg][qt*16+l15]
    float m_i[4], l_i[4];
    #pragma unroll
    for (int qt = 0; qt < 4; ++qt) {
        m_i[qt] = -INFINITY; l_i[qt] = 0.f;
        #pragma unroll
        for (int dt = 0; dt < 4; ++dt) acc[dt][qt] = (f32x4){0.f, 0.f, 0.f, 0.f};
    }

    for (int k0 = 0; k0 < SS; k0 += 64) {
        const int jt = (k0 >> 4) + w;    // this wave's 16-row j-slice

        const half_t* kp = Kf + ((size_t)bh * 144 + jt) * 1024;
        half8 kf[2];
        kf[0] = *(const half8*)(kp + lane * 8);
        kf[1] = *(const half8*)(kp + 512 + lane * 8);

        const half_t* vp = Vf + ((size_t)bh * 144 + jt) * 1024;
        half4 vf[4];
        #pragma unroll
        for (int dt = 0; dt < 4; ++dt)
            vf[dt] = *(const half4*)(vp + dt * 256 + lane * 4);

        // ---- S^T = K . Q^T ----
        f32x4 sc[4];
        #pragma unroll
        for (int qt = 0; qt < 4; ++qt) {
            sc[qt] = (f32x4){0.f, 0.f, 0.f, 0.f};
            #pragma unroll
            for (int dt2 = 0; dt2 < 2; ++dt2)
                sc[qt] = __builtin_amdgcn_mfma_f32_16x16x32_f16(
                    kf[dt2], qf[qt][dt2], sc[qt], 0, 0, 0);
        }

        // ---- online softmax (per q column; lane's 4 regs are 4 j's) ----
        half4 pf[4];
        #pragma unroll
        for (int qt = 0; qt < 4; ++qt) {
            float mx = fmaxf(fmaxf(sc[qt][0], sc[qt][1]), fmaxf(sc[qt][2], sc[qt][3]));
            mx = fmaxf(mx, __shfl_xor(mx, 16));
            mx = fmaxf(mx, __shfl_xor(mx, 32));
            const float mn = fmaxf(m_i[qt], mx);
            const float alpha = __expf(m_i[qt] - mn);
            m_i[qt] = mn;
            const float p0 = __expf(sc[qt][0] - mn);
            const float p1 = __expf(sc[qt][1] - mn);
            const float p2 = __expf(sc[qt][2] - mn);
            const float p3 = __expf(sc[qt][3] - mn);
            float ps = p0 + p1 + p2 + p3;
            ps += __shfl_xor(ps, 16);
            ps += __shfl_xor(ps, 32);
            l_i[qt] = l_i[qt] * alpha + ps;
            #pragma unroll
            for (int dt = 0; dt < 4; ++dt) acc[dt][qt] *= alpha;
            pf[qt] = (half4){(half_t)p0, (half_t)p1, (half_t)p2, (half_t)p3};
        }

        // ---- O^T += V^T . P^T ----
        #pragma unroll
        for (int dt = 0; dt < 4; ++dt)
            #pragma unroll
            for (int qt = 0; qt < 4; ++qt)
                acc[dt][qt] = __builtin_amdgcn_mfma_f32_16x16x16f16(
                    vf[dt], pf[qt], acc[dt][qt], 0, 0, 0);
    }

    // ---- merge the 4 waves' partial (m, l, O^T) ----
    __shared__ float mlb[4][64][2];
    __shared__ float Obuf[64][66];

    if (quad == 0) {
        #pragma unroll
        for (int qt = 0; qt < 4; ++qt) {
            mlb[w][qt * 16 + l15][0] = m_i[qt];
            mlb[w][qt * 16 + l15][1] = l_i[qt];
        }
    }
    __syncthreads();

    float fac[4];
    #pragma unroll
    for (int qt = 0; qt < 4; ++qt) {
        const int q = qt * 16 + l15;
        const float M = fmaxf(fmaxf(mlb[0][q][0], mlb[1][q][0]),
                              fmaxf(mlb[2][q][0], mlb[3][q][0]));
        const float L = mlb[0][q][1] * __expf(mlb[0][q][0] - M)
                      + mlb[1][q][1] * __expf(mlb[1][q][0] - M)
                      + mlb[2][q][1] * __expf(mlb[2][q][0] - M)
                      + mlb[3][q][1] * __expf(mlb[3][q][0] - M);
        fac[qt] = __expf(m_i[qt] - M) / L;
    }

    #pragma unroll
    for (int ph = 0; ph < 4; ++ph) {
        if (w == ph) {
            #pragma unroll
            for (int dt = 0; dt < 4; ++dt)
                #pragma unroll
                for (int qt = 0; qt < 4; ++qt)
                    #pragma unroll
                    for (int rg = 0; rg < 4; ++rg) {
                        const int d = dt * 16 + quad * 4 + rg;
                        const int q = qt * 16 + l15;
                        const float v = acc[dt][qt][rg] * fac[qt];
                        if (ph == 0) Obuf[d][q] = v; else Obuf[d][q] += v;
                    }
        }
        __syncthreads();
    }

    // ---- store O as f16, tile-blocked for the proj GEMM ----
    {
        const int q  = t >> 2;               // 0..63 (token within q-tile)
        const int ds = (t & 3) * 16;         // within-head dim start
        const size_t mrow = tb + q0 + q;     // global token row
        const int mb2 = (int)(mrow >> 7);
        const int mm  = (int)(mrow & 127);
        #pragma unroll
        for (int g = 0; g < 4; ++g) {
            const int dd = ds + 4 * g;       // within-head dim (0..60)
            const int kb2 = (h * HD + dd) >> 5;
            const int kk  = dd & 31;
            half4 o;
            o[0] = (half_t)Obuf[dd + 0][q];
            o[1] = (half_t)Obuf[dd + 1][q];
            o[2] = (half_t)Obuf[dd + 2][q];
            o[3] = (half_t)Obuf[dd + 3][q];
            *(half4*)(attn_h + ((size_t)mb2 * 32 + kb2) * 4096 + mm * 32 + kk) = o;
        }
    }
}

// ---------------------------------------------------------------------------
// Launch
// ---------------------------------------------------------------------------
extern "C" void kernel_launch(void* const* d_in, const int* in_sizes, int n_in,
                              void* d_out, int out_size, void* d_ws, size_t ws_size,
                              hipStream_t stream)
{
    const float* input   = (const float*)d_in[0];
    const float* qkv_w   = (const float*)d_in[1];
    const float* qkv_b   = (const float*)d_in[2];
    const float* q_scale = (const float*)d_in[3];
    const float* k_scale = (const float*)d_in[4];
    const float* proj_w  = (const float*)d_in[5];
    const float* proj_b  = (const float*)d_in[6];
    const int*   width   = (const int*)d_in[8];
    float* out = (float*)d_out;

    // ws layout (all f16): qkv_h 28.3MB | attn_h 9.4 | Vf 9.4 | Ah 9.4 (reused
    // as Kf after GEMM1) | Bh1 6.3 | Bh2 2.1  => 65.0 MB total
    half_t* qkvh   = (half_t*)d_ws;
    half_t* attn_h = qkvh   + (size_t)4608 * 3072;
    half_t* Vf     = attn_h + (size_t)4608 * 1024;
    half_t* Ah     = Vf     + (size_t)32 * 144 * 1024;
    half_t* Bh1    = Ah     + (size_t)4608 * 1024;
    half_t* Bh2    = Bh1    + (size_t)3072 * 1024;
    half_t* Kf     = Ah;    // Ah is dead after GEMM1; Kf is written by normrope

    const int M = BB * SS;   // 4608

    // 0) fp32 -> f16 tile-blocked converters
    convert_tile_f16<<<dim3(M / 128, DINC / 32),    256, 0, stream>>>(input,  Ah,  DINC);
    convert_tile_f16<<<dim3(3 * DIMC / 128, DINC / 32), 256, 0, stream>>>(qkv_w, Bh1, DINC);
    convert_tile_f16<<<dim3(DINC / 128, DIMC / 32), 256, 0, stream>>>(proj_w, Bh2, DIMC);

    // 1) qkv_h = f16( input @ qkv_w^T + qkv_b )
    gemm_mfma<true><<<dim3(3 * DIMC / 128, M / 128), 256, 0, stream>>>(
        Ah, Bh1, qkv_b, qkvh, M, 3 * DIMC, DINC);

    // 2) RMSNorm + RoPE: Q in place, K -> Kf stream, V -> Vf stream
    normrope_v3<<<M, 256, 0, stream>>>(qkvh, q_scale, k_scale, width, Kf, Vf);

    // 3) MFMA flash attention -> attn_h (f16, tile-blocked)
    flash_attn_mfma2<<<dim3(SS / 64, BB * HH), 256, 0, stream>>>(qkvh, Kf, Vf, attn_h);

    // 4) out = attn @ proj_w^T + proj_b  (fp32 out)
    gemm_mfma<false><<<dim3(DINC / 128, M / 128), 256, 0, stream>>>(
        attn_h, Bh2, proj_b, out, M, DINC, DIMC);
}

// Round 5
// 297.252 us; speedup vs baseline: 5.7054x; 1.1214x over previous
//
#include <hip/hip_runtime.h>
#include <math.h>

// Problem constants (fixed by the reference)
#define BB   2
#define SS   2304
#define DINC 1024
#define DIMC 1024
#define HH   16
#define HD   64

typedef _Float16 half_t;
typedef __attribute__((ext_vector_type(4))) _Float16 half4;   // 2 VGPRs
typedef __attribute__((ext_vector_type(8))) _Float16 half8;   // 4 VGPRs
typedef __attribute__((ext_vector_type(4))) float    f32x4;   // 4 VGPRs

__device__ __forceinline__ half4 lo4(half8 x) { return (half4){x[0], x[1], x[2], x[3]}; }
__device__ __forceinline__ half4 hi4(half8 x) { return (half4){x[4], x[5], x[6], x[7]}; }

// async global->LDS, 16B per lane; LDS dest = wave-uniform base + lane*16
#define GLOAD_LDS16(gp, lp)                                                     \
    __builtin_amdgcn_global_load_lds(                                           \
        (const __attribute__((address_space(1))) void*)(gp),                    \
        (__attribute__((address_space(3))) void*)(lp), 16, 0, 0)

// ---------------------------------------------------------------------------
// Converter: fp32 row-major [R][K] -> f16 tile-blocked [R/128][K/32][128][32].
// ---------------------------------------------------------------------------
__global__ __launch_bounds__(256)
void convert_tile_f16(const float* __restrict__ src, half_t* __restrict__ dst, int K)
{
    const int mb = blockIdx.x;
    const int kb = blockIdx.y;
    const int t  = threadIdx.x;
    const int mm = t >> 1;
    const int kk = (t & 1) * 16;
    const float* sp = src + (size_t)(mb * 128 + mm) * K + kb * 32 + kk;
    half_t*      dp = dst + ((size_t)mb * (K >> 5) + kb) * 4096 + mm * 32 + kk;
    #pragma unroll
    for (int g = 0; g < 4; ++g) {
        float4 v = *(const float4*)(sp + 4 * g);
        dp[4 * g + 0] = (half_t)v.x; dp[4 * g + 1] = (half_t)v.y;
        dp[4 * g + 2] = (half_t)v.z; dp[4 * g + 3] = (half_t)v.w;
    }
}

// ---------------------------------------------------------------------------
// f16 MFMA GEMM (NT): C[m][n] = sum_k A[m][k]*W[n][k] + bias[n], fp32 accum.
// 128x128 block tile, K-loop unrolled x2 (BK=64 effective): 32 MFMAs between
// barriers, staging via global_load_lds dwordx4 (8 x 1KB wave-loads/iter).
// ---------------------------------------------------------------------------
template<bool OUT_HALF>
__global__ __launch_bounds__(256)
void gemm_mfma(const half_t* __restrict__ Ah, const half_t* __restrict__ Bh,
               const float* __restrict__ bias, void* __restrict__ Cout,
               int M, int N, int K)
{
    const int KB = K >> 5;
    __shared__ half_t As[8192];   // [u][128][32]
    __shared__ half_t Bs[8192];

    const int t    = threadIdx.x;
    const int w    = t >> 6;
    const int lane = t & 63;
    const int l15  = lane & 15, quad = lane >> 4;
    const int wr   = w >> 1, wc = w & 1;
    const int mb   = blockIdx.y, nb = blockIdx.x;

    f32x4 acc[4][4];
    #pragma unroll
    for (int mt = 0; mt < 4; ++mt)
        #pragma unroll
        for (int nt = 0; nt < 4; ++nt) acc[mt][nt] = (f32x4){0.f, 0.f, 0.f, 0.f};

    const half_t* atile = Ah + (size_t)mb * KB * 4096;
    const half_t* btile = Bh + (size_t)nb * KB * 4096;

    for (int kb = 0; kb < KB; kb += 2) {
        #pragma unroll
        for (int u = 0; u < 2; ++u) {
            const half_t* at = atile + (size_t)(kb + u) * 4096;
            const half_t* bt = btile + (size_t)(kb + u) * 4096;
            #pragma unroll
            for (int v = 0; v < 2; ++v) {
                const int ch = w * 2 + v;            // 1KB chunk id (0..7)
                GLOAD_LDS16(at + ch * 512 + lane * 8, As + u * 4096 + ch * 512);
                GLOAD_LDS16(bt + ch * 512 + lane * 8, Bs + u * 4096 + ch * 512);
            }
        }
        __syncthreads();

        #pragma unroll
        for (int u = 0; u < 2; ++u) {
            half8 af[4], bf[4];
            #pragma unroll
            for (int mt = 0; mt < 4; ++mt)
                af[mt] = *(const half8*)(As + u * 4096
                                         + (wr * 64 + mt * 16 + l15) * 32 + quad * 8);
            #pragma unroll
            for (int nt = 0; nt < 4; ++nt)
                bf[nt] = *(const half8*)(Bs + u * 4096
                                         + (wc * 64 + nt * 16 + l15) * 32 + quad * 8);
            #pragma unroll
            for (int mt = 0; mt < 4; ++mt)
                #pragma unroll
                for (int nt = 0; nt < 4; ++nt)
                    acc[mt][nt] = __builtin_amdgcn_mfma_f32_16x16x32_f16(
                        af[mt], bf[nt], acc[mt][nt], 0, 0, 0);
        }
        __syncthreads();
    }

    // epilogue: D[m = quad*4+reg][n = l15] per 16x16 tile, + bias
    const int bm = mb * 128, bn = nb * 128;
    #pragma unroll
    for (int nt = 0; nt < 4; ++nt) {
        const int n  = bn + wc * 64 + nt * 16 + l15;
        const float bv = bias[n];
        #pragma unroll
        for (int mt = 0; mt < 4; ++mt) {
            const int m0 = bm + wr * 64 + mt * 16 + quad * 4;
            #pragma unroll
            for (int rg = 0; rg < 4; ++rg) {
                const float v = acc[mt][nt][rg] + bv;
                if (OUT_HALF) ((half_t*)Cout)[(size_t)(m0 + rg) * N + n] = (half_t)v;
                else          ((float*) Cout)[(size_t)(m0 + rg) * N + n] = v;
            }
        }
    }
}

// ---------------------------------------------------------------------------
// RMSNorm (full 1024) + axial 2D RoPE on the f16 qkv buffer (fp32 math).
//  - Q (scaled by 0.125, rotated) -> written back in place (halfs [0,1024))
//  - K (rotated) -> Kf A-fragment stream for the K=32 QK^T MFMA:
//      Kf[(bh*144+jt)*1024 + dt2*512 + (quad*16+l15)*8 + i]
//  - V -> Vf lane-major A-fragment stream for the K=16 PV MFMA:
//      Vf[(bh*144+jt)*1024 + lane*16 + dt*4 + i]  (lane = (j&15)>>2 * 16 + (d&15))
// ---------------------------------------------------------------------------
__global__ __launch_bounds__(256)
void normrope_v4(half_t* __restrict__ qkvh, const float* __restrict__ q_scale,
                 const float* __restrict__ k_scale, const int* __restrict__ wptr,
                 half_t* __restrict__ Kf, half_t* __restrict__ Vf)
{
    const int token = blockIdx.x;        // b*SS + s
    const int s     = token % SS;
    const int b     = token / SS;
    const int w     = *wptr;
    const int t     = threadIdx.x;
    const float rowp = (float)(s / w);
    const float colp = (float)(s % w);

    half_t* base = qkvh + (size_t)token * 3072;

    // ---- V -> Vf fragment stream (lane-major) ----
    {
        half4 v4 = *(const half4*)(base + 2048 + 4 * t);
        const int dabs0 = 4 * t;
        const int h  = dabs0 >> 6;
        const size_t blk = ((size_t)(b * HH + h) * 144 + (s >> 4)) * 1024;
        const int qv = (s & 15) >> 2;
        const int iv = s & 3;
        #pragma unroll
        for (int ii = 0; ii < 4; ++ii) {
            const int d = (dabs0 + ii) & 63;
            Vf[blk + (size_t)(qv * 16 + (d & 15)) * 16 + (d >> 4) * 4 + iv] = v4[ii];
        }
    }

    __shared__ float buf[DIMC];
    __shared__ float red[4];

    #pragma unroll
    for (int sel = 0; sel < 2; ++sel) {
        half_t* row = base + sel * DIMC;
        const float* scp = sel ? k_scale : q_scale;

        half4 xh = *(const half4*)(row + 4 * t);
        float x0 = (float)xh[0], x1 = (float)xh[1], x2 = (float)xh[2], x3 = (float)xh[3];
        float ss = x0 * x0 + x1 * x1 + x2 * x2 + x3 * x3;
        #pragma unroll
        for (int o = 32; o >= 1; o >>= 1) ss += __shfl_xor(ss, o);
        if ((t & 63) == 0) red[t >> 6] = ss;
        __syncthreads();

        const float rinv = rsqrtf((red[0] + red[1] + red[2] + red[3]) * (1.0f / DIMC) + 1e-6f);
        float4 g = *(const float4*)(scp + 4 * t);
        buf[4 * t + 0] = x0 * rinv * g.x;
        buf[4 * t + 1] = x1 * rinv * g.y;
        buf[4 * t + 2] = x2 * rinv * g.z;
        buf[4 * t + 3] = x3 * rinv * g.w;
        __syncthreads();

        const float qsc = sel ? 1.0f : 0.125f;   // fold 1/sqrt(64) into Q

        #pragma unroll
        for (int pp = 0; pp < 2; ++pp) {
            const int p = t + pp * 256;
            const int h = p >> 5;
            const int r = p & 31;
            const int j = r & 15;
            const float pos = (r < 16) ? rowp : colp;
            const int d1 = (r < 16) ? j : (32 + j);   // within-head dim
            const int d2 = d1 + 16;
            // freq = 10000^(-j/16) = exp2(-j * log2(10000)/16)
            const float freq = exp2f((float)j * -0.83048202372f);
            const float ang  = pos * freq;
            float sn, cs;
            __sincosf(ang, &sn, &cs);
            const float a1 = buf[h * HD + d1], a2 = buf[h * HD + d2];
            const float o1 = (a1 * cs - a2 * sn) * qsc;
            const float o2 = (a2 * cs + a1 * sn) * qsc;
            if (sel == 0) {
                row[h * HD + d1] = (half_t)o1;
                row[h * HD + d2] = (half_t)o2;
            } else {
                const size_t kblk = ((size_t)(b * HH + h) * 144 + (s >> 4)) * 1024;
                const int l15k = s & 15;
                Kf[kblk + (size_t)(d1 >> 5) * 512
                        + (((size_t)((d1 & 31) >> 3)) * 16 + l15k) * 8 + (d1 & 7)] = (half_t)o1;
                Kf[kblk + (size_t)(d2 >> 5) * 512
                        + (((size_t)((d2 & 31) >> 3)) * 16 + l15k) * 8 + (d2 & 7)] = (half_t)o2;
            }
        }
        __syncthreads();   // buf/red reused by next sel
    }
}

// ---------------------------------------------------------------------------
// Flash attention v3 on the matrix pipe. Per block iteration each of the 4
// waves processes TWO consecutive 16-row j-tiles under ONE softmax frame
// (halves per-j rescale/shuffle cost). Skip-rescale uniform branch when no
// lane's max grew; lane-local l accumulation (reduced once at epilogue).
// S^T C-layout rows (j=quad*4+reg) feed the PV MFMA B-operand directly.
// ---------------------------------------------------------------------------
__global__ __launch_bounds__(256)
void flash_attn_mfma3(const half_t* __restrict__ qkvh, const half_t* __restrict__ Kf,
                      const half_t* __restrict__ Vf, half_t* __restrict__ attn_h)
{
    const int qtb = blockIdx.x;          // 0..35
    const int bh  = blockIdx.y;          // 0..31
    const int b   = bh >> 4, h = bh & 15;
    const int t   = threadIdx.x;
    const int w   = t >> 6;
    const int lane = t & 63;
    const int l15 = lane & 15, quad = lane >> 4;

    const size_t tb = (size_t)b * SS;
    const int q0 = qtb * 64;

    // Q B-frags (loop invariant): B[k=quad*8+i][n=l15]
    half8 qf[4][2];
    #pragma unroll
    for (int qt = 0; qt < 4; ++qt)
        #pragma unroll
        for (int dt2 = 0; dt2 < 2; ++dt2)
            qf[qt][dt2] = *(const half8*)(qkvh + (tb + q0 + qt * 16 + l15) * 3072
                                          + h * HD + dt2 * 32 + quad * 8);

    f32x4 acc[4][4];                     // [dt][qt] : O^T[dt*16+quad*4+reg][qt*16+l15]
    float m_i[4], l_i[4];                // l is LANE-LOCAL partial
    #pragma unroll
    for (int qt = 0; qt < 4; ++qt) {
        m_i[qt] = -INFINITY; l_i[qt] = 0.f;
        #pragma unroll
        for (int dt = 0; dt < 4; ++dt) acc[dt][qt] = (f32x4){0.f, 0.f, 0.f, 0.f};
    }

    const half_t* kbase = Kf + (size_t)bh * 144 * 1024;
    const half_t* vbase = Vf + (size_t)bh * 144 * 1024;

    for (int kb2 = 0; kb2 < SS / 128; ++kb2) {
        const int jtA = kb2 * 8 + 2 * w;     // wave's two consecutive j-tiles

        const half_t* kp = kbase + (size_t)jtA * 1024;
        half8 kfA[2], kfB[2];
        kfA[0] = *(const half8*)(kp + lane * 8);
        kfA[1] = *(const half8*)(kp + 512 + lane * 8);
        kfB[0] = *(const half8*)(kp + 1024 + lane * 8);
        kfB[1] = *(const half8*)(kp + 1536 + lane * 8);

        const half_t* vp = vbase + (size_t)jtA * 1024 + lane * 16;
        half8 vA01 = *(const half8*)(vp);
        half8 vA23 = *(const half8*)(vp + 8);
        half8 vB01 = *(const half8*)(vp + 1024);
        half8 vB23 = *(const half8*)(vp + 1032);
        half4 vfA[4] = {lo4(vA01), hi4(vA01), lo4(vA23), hi4(vA23)};
        half4 vfB[4] = {lo4(vB01), hi4(vB01), lo4(vB23), hi4(vB23)};

        // ---- S^T = K . Q^T for both j-tiles ----
        f32x4 scA[4], scB[4];
        #pragma unroll
        for (int qt = 0; qt < 4; ++qt) {
            scA[qt] = (f32x4){0.f, 0.f, 0.f, 0.f};
            scB[qt] = (f32x4){0.f, 0.f, 0.f, 0.f};
            #pragma unroll
            for (int dt2 = 0; dt2 < 2; ++dt2) {
                scA[qt] = __builtin_amdgcn_mfma_f32_16x16x32_f16(
                    kfA[dt2], qf[qt][dt2], scA[qt], 0, 0, 0);
                scB[qt] = __builtin_amdgcn_mfma_f32_16x16x32_f16(
                    kfB[dt2], qf[qt][dt2], scB[qt], 0, 0, 0);
            }
        }

        // ---- online softmax: one frame per 32 j's ----
        half4 pfA[4], pfB[4];
        #pragma unroll
        for (int qt = 0; qt < 4; ++qt) {
            float mx = fmaxf(fmaxf(fmaxf(scA[qt][0], scA[qt][1]),
                                   fmaxf(scA[qt][2], scA[qt][3])),
                             fmaxf(fmaxf(scB[qt][0], scB[qt][1]),
                                   fmaxf(scB[qt][2], scB[qt][3])));
            mx = fmaxf(mx, __shfl_xor(mx, 16));
            mx = fmaxf(mx, __shfl_xor(mx, 32));
            if (__any(mx > m_i[qt])) {       // uniform branch: rescale needed
                const float mn = fmaxf(m_i[qt], mx);
                const float alpha = __expf(m_i[qt] - mn);
                m_i[qt] = mn;
                l_i[qt] *= alpha;
                #pragma unroll
                for (int dt = 0; dt < 4; ++dt) acc[dt][qt] *= alpha;
            }
            const float m = m_i[qt];
            const float pA0 = __expf(scA[qt][0] - m);
            const float pA1 = __expf(scA[qt][1] - m);
            const float pA2 = __expf(scA[qt][2] - m);
            const float pA3 = __expf(scA[qt][3] - m);
            const float pB0 = __expf(scB[qt][0] - m);
            const float pB1 = __expf(scB[qt][1] - m);
            const float pB2 = __expf(scB[qt][2] - m);
            const float pB3 = __expf(scB[qt][3] - m);
            l_i[qt] += (pA0 + pA1 + pA2 + pA3) + (pB0 + pB1 + pB2 + pB3);
            pfA[qt] = (half4){(half_t)pA0, (half_t)pA1, (half_t)pA2, (half_t)pA3};
            pfB[qt] = (half4){(half_t)pB0, (half_t)pB1, (half_t)pB2, (half_t)pB3};
        }

        // ---- O^T += V^T . P^T (both j-tiles) ----
        #pragma unroll
        for (int dt = 0; dt < 4; ++dt)
            #pragma unroll
            for (int qt = 0; qt < 4; ++qt) {
                acc[dt][qt] = __builtin_amdgcn_mfma_f32_16x16x16f16(
                    vfA[dt], pfA[qt], acc[dt][qt], 0, 0, 0);
                acc[dt][qt] = __builtin_amdgcn_mfma_f32_16x16x16f16(
                    vfB[dt], pfB[qt], acc[dt][qt], 0, 0, 0);
            }
    }

    // ---- merge the 4 waves' partial (m, l, O^T) ----
    __shared__ float mlb[4][64][2];
    __shared__ float Obuf[64][66];

    if (quad == 0) {
        #pragma unroll
        for (int qt = 0; qt < 4; ++qt)
            mlb[w][qt * 16 + l15][0] = m_i[qt];
    }
    #pragma unroll
    for (int qt = 0; qt < 4; ++qt) {      // reduce lane-local l across quads
        float lq = l_i[qt];
        lq += __shfl_xor(lq, 16);
        lq += __shfl_xor(lq, 32);
        if (quad == 0) mlb[w][qt * 16 + l15][1] = lq;
    }
    __syncthreads();

    float fac[4];
    #pragma unroll
    for (int qt = 0; qt < 4; ++qt) {
        const int q = qt * 16 + l15;
        const float M = fmaxf(fmaxf(mlb[0][q][0], mlb[1][q][0]),
                              fmaxf(mlb[2][q][0], mlb[3][q][0]));
        const float L = mlb[0][q][1] * __expf(mlb[0][q][0] - M)
                      + mlb[1][q][1] * __expf(mlb[1][q][0] - M)
                      + mlb[2][q][1] * __expf(mlb[2][q][0] - M)
                      + mlb[3][q][1] * __expf(mlb[3][q][0] - M);
        fac[qt] = __expf(m_i[qt] - M) / L;
    }

    #pragma unroll
    for (int ph = 0; ph < 4; ++ph) {
        if (w == ph) {
            #pragma unroll
            for (int dt = 0; dt < 4; ++dt)
                #pragma unroll
                for (int qt = 0; qt < 4; ++qt)
                    #pragma unroll
                    for (int rg = 0; rg < 4; ++rg) {
                        const int d = dt * 16 + quad * 4 + rg;
                        const int q = qt * 16 + l15;
                        const float v = acc[dt][qt][rg] * fac[qt];
                        if (ph == 0) Obuf[d][q] = v; else Obuf[d][q] += v;
                    }
        }
        __syncthreads();
    }

    // ---- store O as f16, tile-blocked [mb][kb][128][32] for the proj GEMM ----
    {
        const int q  = t >> 2;               // token within q-tile
        const int ds = (t & 3) * 16;
        const size_t mrow = tb + q0 + q;
        const int mb2 = (int)(mrow >> 7);
        const int mm  = (int)(mrow & 127);
        #pragma unroll
        for (int g = 0; g < 4; ++g) {
            const int dd = ds + 4 * g;
            const int kb2 = (h * HD + dd) >> 5;
            const int kk  = dd & 31;
            half4 o;
            o[0] = (half_t)Obuf[dd + 0][q];
            o[1] = (half_t)Obuf[dd + 1][q];
            o[2] = (half_t)Obuf[dd + 2][q];
            o[3] = (half_t)Obuf[dd + 3][q];
            *(half4*)(attn_h + ((size_t)mb2 * 32 + kb2) * 4096 + mm * 32 + kk) = o;
        }
    }
}

// ---------------------------------------------------------------------------
// Launch
// ---------------------------------------------------------------------------
extern "C" void kernel_launch(void* const* d_in, const int* in_sizes, int n_in,
                              void* d_out, int out_size, void* d_ws, size_t ws_size,
                              hipStream_t stream)
{
    const float* input   = (const float*)d_in[0];
    const float* qkv_w   = (const float*)d_in[1];
    const float* qkv_b   = (const float*)d_in[2];
    const float* q_scale = (const float*)d_in[3];
    const float* k_scale = (const float*)d_in[4];
    const float* proj_w  = (const float*)d_in[5];
    const float* proj_b  = (const float*)d_in[6];
    const int*   width   = (const int*)d_in[8];
    float* out = (float*)d_out;

    // ws layout (all f16): qkv_h 28.3MB | attn_h 9.4 | Vf 9.4 | Ah 9.4 (reused
    // as Kf after GEMM1) | Bh1 6.3 | Bh2 2.1  => 65.0 MB total
    half_t* qkvh   = (half_t*)d_ws;
    half_t* attn_h = qkvh   + (size_t)4608 * 3072;
    half_t* Vf     = attn_h + (size_t)4608 * 1024;
    half_t* Ah     = Vf     + (size_t)32 * 144 * 1024;
    half_t* Bh1    = Ah     + (size_t)4608 * 1024;
    half_t* Bh2    = Bh1    + (size_t)3072 * 1024;
    half_t* Kf     = Ah;    // Ah is dead after GEMM1; Kf is written by normrope

    const int M = BB * SS;   // 4608

    // 0) fp32 -> f16 tile-blocked converters
    convert_tile_f16<<<dim3(M / 128, DINC / 32),    256, 0, stream>>>(input,  Ah,  DINC);
    convert_tile_f16<<<dim3(3 * DIMC / 128, DINC / 32), 256, 0, stream>>>(qkv_w, Bh1, DINC);
    convert_tile_f16<<<dim3(DINC / 128, DIMC / 32), 256, 0, stream>>>(proj_w, Bh2, DIMC);

    // 1) qkv_h = f16( input @ qkv_w^T + qkv_b )
    gemm_mfma<true><<<dim3(3 * DIMC / 128, M / 128), 256, 0, stream>>>(
        Ah, Bh1, qkv_b, qkvh, M, 3 * DIMC, DINC);

    // 2) RMSNorm + RoPE: Q in place, K -> Kf stream, V -> Vf stream
    normrope_v4<<<M, 256, 0, stream>>>(qkvh, q_scale, k_scale, width, Kf, Vf);

    // 3) MFMA flash attention -> attn_h (f16, tile-blocked)
    flash_attn_mfma3<<<dim3(SS / 64, BB * HH), 256, 0, stream>>>(qkvh, Kf, Vf, attn_h);

    // 4) out = attn @ proj_w^T + proj_b  (fp32 out)
    gemm_mfma<false><<<dim3(DINC / 128, M / 128), 256, 0, stream>>>(
        attn_h, Bh2, proj_b, out, M, DINC, DIMC);
}